// Round 9
// baseline (14.902 us; speedup 1.0000x reference)
//
#include <hip/hip_runtime.h>

#define EPSV 1e-7f

// v11: register-tier fix, zero-inst-cost. v10's peak live set audit: Cb 36 +
// Xb 36 + moment partial ARRAYS 36 + window sums 18 + adj/mu/temps ~35 =
// ~130-145 VGPR => over the 128 cliff => 3 waves/SIMD, not the assumed 4.
// Fix: compute each moment/X quantity ONE AT A TIME (A0, A1, WSUM, retire) --
// identical op sequence (bitwise-equal numerics to v10), but the 56-reg
// partial-array lifetime vanishes. New peak ~105-110 VGPR => 4 waves/SIMD.
// Kept: 2-win/thread, packed f2 math, X-hoist burst, WSUM=pk+2scalar,
// unnormalized adjugate, v_rcp_f32, XCD swizzle, store+reducer ending.
// Pre-committed: 12.5-13.5us => cliff was real; neutral => regs dead as
// lever, attack dispatch/dep-chain floor next; regression => ILP loss.
typedef float f2 __attribute__((ext_vector_type(2)));

__global__ __launch_bounds__(256) void matting_loss_kernel(
    const float* __restrict__ outp, const float* __restrict__ cont,
    float* __restrict__ ws)
{
    const int H = 512, W = 512, NW = 510;
    const int HW = H * W;

    // --- XCD swizzle (bijective: 2048 % 8 == 0) ---
    const int lin = blockIdx.x + 8 * (blockIdx.y + 64 * blockIdx.z);
    const int swz = (lin & 7) * 256 + (lin >> 3);
    const int b   = swz >> 9;                       // image 0..3
    const int rem = swz & 511;
    const int gx  = (rem & 7) * 32 + threadIdx.x;   // 0..255 -> wx0 = 2*gx
    const int gy  = (rem >> 3) * 8 + threadIdx.y;   // 0..511 -> window row
    const int wx0 = gx * 2;
    const int wy  = gy;

    const float* Cin = cont + (size_t)b * 3 * HW;
    const float* Xin = outp + (size_t)b * 3 * HW;

    float contrib = 0.0f;
    const float inv9 = 1.0f / 9.0f;

    // {w0,w1} from column-pair partials A0={c0,c1}, A1={c2,c3}:
    // T=A0+A1 packed; w0=T.x+A0.y, w1=T.y+A1.x (2 scalar adds, no repack).
#define WSUM(OUT, A0, A1) { f2 T_ = (A0) + (A1); (OUT).x = T_.x + (A0).y; (OUT).y = T_.y + (A1).x; }
    // Per-quantity forms: partials live only inside the braces (reg diet).
#define CSUM(CH, OUT) { \
    f2 A0_ = Cb[CH][0][0] + Cb[CH][1][0] + Cb[CH][2][0]; \
    f2 A1_ = Cb[CH][0][1] + Cb[CH][1][1] + Cb[CH][2][1]; \
    WSUM(OUT, A0_, A1_) }
#define CDOT(CA, CB_, OUT) { \
    f2 A0_ = Cb[CA][0][0]*Cb[CB_][0][0] + Cb[CA][1][0]*Cb[CB_][1][0] + Cb[CA][2][0]*Cb[CB_][2][0]; \
    f2 A1_ = Cb[CA][0][1]*Cb[CB_][0][1] + Cb[CA][1][1]*Cb[CB_][1][1] + Cb[CA][2][1]*Cb[CB_][2][1]; \
    WSUM(OUT, A0_, A1_) }
#define XSUM(C_, OUT) { \
    f2 A0_ = Xb[C_][0][0] + Xb[C_][1][0] + Xb[C_][2][0]; \
    f2 A1_ = Xb[C_][0][1] + Xb[C_][1][1] + Xb[C_][2][1]; \
    WSUM(OUT, A0_, A1_) }
#define XXDOT(C_, OUT) { \
    f2 A0_ = Xb[C_][0][0]*Xb[C_][0][0] + Xb[C_][1][0]*Xb[C_][1][0] + Xb[C_][2][0]*Xb[C_][2][0]; \
    f2 A1_ = Xb[C_][0][1]*Xb[C_][0][1] + Xb[C_][1][1]*Xb[C_][1][1] + Xb[C_][2][1]*Xb[C_][2][1]; \
    WSUM(OUT, A0_, A1_) }
#define XCDOT(C_, K_, OUT) { \
    f2 A0_ = Xb[C_][0][0]*Cb[K_][0][0] + Xb[C_][1][0]*Cb[K_][1][0] + Xb[C_][2][0]*Cb[K_][2][0]; \
    f2 A1_ = Xb[C_][0][1]*Cb[K_][0][1] + Xb[C_][1][1]*Cb[K_][1][1] + Xb[C_][2][1]*Cb[K_][2][1]; \
    WSUM(OUT, A0_, A1_) }

    if (wy < NW && wx0 < NW) {     // wx0 <= 508: windows wx0, wx0+1 both valid
        const int base = wy * W + wx0;

        // One load burst: 18 C + 18 X f2 loads, all in flight together.
        f2 Cb[3][3][2];   // [ch][row][colpair]
        f2 Xb[3][3][2];
        #pragma unroll
        for (int ch = 0; ch < 3; ++ch)
            #pragma unroll
            for (int r = 0; r < 3; ++r) {
                const float* p = Cin + ch * HW + base + r * W;
                Cb[ch][r][0] = *(const f2*)p;
                Cb[ch][r][1] = *(const f2*)(p + 2);
                const float* q = Xin + ch * HW + base + r * W;
                Xb[ch][r][0] = *(const f2*)q;
                Xb[ch][r][1] = *(const f2*)(q + 2);
            }

        // --- Moment phase: per-quantity window sums (no partial arrays) ---
        f2 sI0, sI1, sI2, s00, s01, s02, s11, s12, s22;
        CSUM(0, sI0) CSUM(1, sI1) CSUM(2, sI2)
        CDOT(0, 0, s00) CDOT(0, 1, s01) CDOT(0, 2, s02)
        CDOT(1, 1, s11) CDOT(1, 2, s12) CDOT(2, 2, s22)

        // Packed mu + adjugate of the regularized covariance (both windows).
        f2 mu0 = sI0 * inv9, mu1 = sI1 * inv9, mu2 = sI2 * inv9;
        const float ed = EPSV * inv9;
        f2 v00 = s00 * inv9 - mu0 * mu0 + ed;
        f2 v01 = s01 * inv9 - mu0 * mu1;
        f2 v02 = s02 * inv9 - mu0 * mu2;
        f2 v11 = s11 * inv9 - mu1 * mu1 + ed;
        f2 v12 = s12 * inv9 - mu1 * mu2;
        f2 v22 = s22 * inv9 - mu2 * mu2 + ed;
        f2 adj0 = v11 * v22 - v12 * v12;   // adj00
        f2 adj1 = v02 * v12 - v01 * v22;   // adj01
        f2 adj2 = v01 * v12 - v02 * v11;   // adj02
        f2 adj3 = v00 * v22 - v02 * v02;   // adj11
        f2 adj4 = v01 * v02 - v00 * v12;   // adj12
        f2 adj5 = v00 * v11 - v01 * v01;   // adj22
        f2 det = v00 * adj0 + v01 * adj1 + v02 * adj2;
        f2 id;
        id.x = __builtin_amdgcn_rcpf(det.x);   // v_rcp_f32 (validated v3..v10)
        id.y = __builtin_amdgcn_rcpf(det.y);

        // --- X phase: per-quantity window sums -> packed window quadratic ---
        f2 termAcc = (f2){0.0f, 0.0f};
        #pragma unroll
        for (int c = 0; c < 3; ++c) {
            f2 S, SSw, W0, W1, W2;
            XSUM(c, S) XXDOT(c, SSw)
            XCDOT(c, 0, W0) XCDOT(c, 1, W1) XCDOT(c, 2, W2)
            f2 u0 = W0 - S * mu0;
            f2 u1 = W1 - S * mu1;
            f2 u2 = W2 - S * mu2;
            f2 qa = u0 * (adj0 * u0 + adj1 * u1 + adj2 * u2)
                  + u1 * (adj1 * u0 + adj3 * u1 + adj4 * u2)
                  + u2 * (adj2 * u0 + adj4 * u1 + adj5 * u2);
            termAcc += SSw - (S * S + qa * id) * inv9;
        }
        contrib = termAcc.x + termAcc.y;       // both windows valid
    }
#undef WSUM
#undef CSUM
#undef CDOT
#undef XSUM
#undef XXDOT
#undef XCDOT

    // Wave shuffle reduction -> cross-wave LDS -> ONE plain store per block.
    #pragma unroll
    for (int off = 32; off > 0; off >>= 1)
        contrib += __shfl_down(contrib, off, 64);

    __shared__ float wsum[4];
    const int tid = threadIdx.y * 32 + threadIdx.x;
    const int lane = tid & 63, wv = tid >> 6;
    if (lane == 0) wsum[wv] = contrib;
    __syncthreads();
    if (tid == 0)
        ws[swz] = wsum[0] + wsum[1] + wsum[2] + wsum[3];
}

// Tiny reducer: image b owns ws[b*512 .. b*512+511]. Writes loss[b] directly.
__global__ __launch_bounds__(256) void reduce_kernel(
    const float* __restrict__ ws, float* __restrict__ loss)
{
    const int b = blockIdx.x;
    const int t = threadIdx.x;
    float v = ws[b * 512 + t] + ws[b * 512 + 256 + t];
    #pragma unroll
    for (int off = 32; off > 0; off >>= 1)
        v += __shfl_down(v, off, 64);

    __shared__ float s[4];
    if ((t & 63) == 0) s[t >> 6] = v;
    __syncthreads();
    if (t == 0) loss[b] = s[0] + s[1] + s[2] + s[3];
}

extern "C" void kernel_launch(void* const* d_in, const int* in_sizes, int n_in,
                              void* d_out, int out_size, void* d_ws, size_t ws_size,
                              hipStream_t stream) {
    const float* outp = (const float*)d_in[0];   // output: (4,3,512,512) f32
    const float* cont = (const float*)d_in[1];   // content: (4,3,512,512) f32
    float* loss = (float*)d_out;                 // (4,1,1) f32
    float* ws   = (float*)d_ws;                  // 2048 floats of workspace

    dim3 block(32, 8, 1);
    dim3 grid(8, 64, 4);   // 256 thread-cols x 512 thread-rows x 4 images
    matting_loss_kernel<<<grid, block, 0, stream>>>(outp, cont, ws);
    reduce_kernel<<<dim3(4, 1, 1), dim3(256, 1, 1), 0, stream>>>(ws, loss);
}

// Round 10
// 14.408 us; speedup vs baseline: 1.0343x; 1.0343x over previous
//
#include <hip/hip_runtime.h>

#define EPSV 1e-7f

// v12: secure the 4-waves/SIMD tier. Evidence: dT == dIssueCycles exactly at
// the margin (v8->v9: pred 2.8us, meas 2.7; v10: pred 0.2, meas 0.14), but
// total time is 4x the issue floor => time = C + issue, C~9us of exposed
// memory latency => too few co-resident waves. Never observed unpinned VGPR;
// unpinned allocators spend >128 freely. Fix: (1) reg diet: X held per-channel
// (12 regs) with next-ch prefetch (v2/v4 pattern, inst-neutral) instead of 36;
// peak ~110 VGPR. (2) __launch_bounds__(256,4) pins the 128-reg/4-wave tier --
// now SAFE (packed body fits; v5's spill was the scalar ~150-reg body).
// Kept: packed f2 math, per-quantity WSUM, unnorm adjugate, v_rcp, XCD
// swizzle, contention-free store + reducer.
typedef float f2 __attribute__((ext_vector_type(2)));

__global__ __launch_bounds__(256, 4) void matting_loss_kernel(
    const float* __restrict__ outp, const float* __restrict__ cont,
    float* __restrict__ ws)
{
    const int H = 512, W = 512, NW = 510;
    const int HW = H * W;

    // --- XCD swizzle (bijective: 2048 % 8 == 0) ---
    const int lin = blockIdx.x + 8 * (blockIdx.y + 64 * blockIdx.z);
    const int swz = (lin & 7) * 256 + (lin >> 3);
    const int b   = swz >> 9;                       // image 0..3
    const int rem = swz & 511;
    const int gx  = (rem & 7) * 32 + threadIdx.x;   // 0..255 -> wx0 = 2*gx
    const int gy  = (rem >> 3) * 8 + threadIdx.y;   // 0..511 -> window row
    const int wx0 = gx * 2;
    const int wy  = gy;

    const float* Cin = cont + (size_t)b * 3 * HW;
    const float* Xin = outp + (size_t)b * 3 * HW;

    float contrib = 0.0f;
    const float inv9 = 1.0f / 9.0f;

#define WSUM(OUT, A0, A1) { f2 T_ = (A0) + (A1); (OUT).x = T_.x + (A0).y; (OUT).y = T_.y + (A1).x; }
#define CSUM(CH, OUT) { \
    f2 A0_ = Cb[CH][0][0] + Cb[CH][1][0] + Cb[CH][2][0]; \
    f2 A1_ = Cb[CH][0][1] + Cb[CH][1][1] + Cb[CH][2][1]; \
    WSUM(OUT, A0_, A1_) }
#define CDOT(CA, CB_, OUT) { \
    f2 A0_ = Cb[CA][0][0]*Cb[CB_][0][0] + Cb[CA][1][0]*Cb[CB_][1][0] + Cb[CA][2][0]*Cb[CB_][2][0]; \
    f2 A1_ = Cb[CA][0][1]*Cb[CB_][0][1] + Cb[CA][1][1]*Cb[CB_][1][1] + Cb[CA][2][1]*Cb[CB_][2][1]; \
    WSUM(OUT, A0_, A1_) }
#define XSUM(XB, OUT) { \
    f2 A0_ = XB[0][0] + XB[1][0] + XB[2][0]; \
    f2 A1_ = XB[0][1] + XB[1][1] + XB[2][1]; \
    WSUM(OUT, A0_, A1_) }
#define XXDOT(XB, OUT) { \
    f2 A0_ = XB[0][0]*XB[0][0] + XB[1][0]*XB[1][0] + XB[2][0]*XB[2][0]; \
    f2 A1_ = XB[0][1]*XB[0][1] + XB[1][1]*XB[1][1] + XB[2][1]*XB[2][1]; \
    WSUM(OUT, A0_, A1_) }
#define XCDOT(XB, K_, OUT) { \
    f2 A0_ = XB[0][0]*Cb[K_][0][0] + XB[1][0]*Cb[K_][1][0] + XB[2][0]*Cb[K_][2][0]; \
    f2 A1_ = XB[0][1]*Cb[K_][0][1] + XB[1][1]*Cb[K_][1][1] + XB[2][1]*Cb[K_][2][1]; \
    WSUM(OUT, A0_, A1_) }

    if (wy < NW && wx0 < NW) {     // wx0 <= 508: windows wx0, wx0+1 both valid
        const int base = wy * W + wx0;

        // Load burst: 18 C f2 loads + channel-0 X rows (6 f2), in flight
        // together; latency hides under the moment phase.
        f2 Cb[3][3][2];   // [ch][row][colpair]
        #pragma unroll
        for (int ch = 0; ch < 3; ++ch)
            #pragma unroll
            for (int r = 0; r < 3; ++r) {
                const float* p = Cin + ch * HW + base + r * W;
                Cb[ch][r][0] = *(const f2*)p;
                Cb[ch][r][1] = *(const f2*)(p + 2);
            }
        f2 Xcur[3][2];
        #pragma unroll
        for (int r = 0; r < 3; ++r) {
            const float* q = Xin + base + r * W;
            Xcur[r][0] = *(const f2*)q;
            Xcur[r][1] = *(const f2*)(q + 2);
        }

        // --- Moment phase: per-quantity window sums ---
        f2 sI0, sI1, sI2, s00, s01, s02, s11, s12, s22;
        CSUM(0, sI0) CSUM(1, sI1) CSUM(2, sI2)
        CDOT(0, 0, s00) CDOT(0, 1, s01) CDOT(0, 2, s02)
        CDOT(1, 1, s11) CDOT(1, 2, s12) CDOT(2, 2, s22)

        // Packed mu + adjugate of the regularized covariance (both windows).
        f2 mu0 = sI0 * inv9, mu1 = sI1 * inv9, mu2 = sI2 * inv9;
        const float ed = EPSV * inv9;
        f2 v00 = s00 * inv9 - mu0 * mu0 + ed;
        f2 v01 = s01 * inv9 - mu0 * mu1;
        f2 v02 = s02 * inv9 - mu0 * mu2;
        f2 v11 = s11 * inv9 - mu1 * mu1 + ed;
        f2 v12 = s12 * inv9 - mu1 * mu2;
        f2 v22 = s22 * inv9 - mu2 * mu2 + ed;
        f2 adj0 = v11 * v22 - v12 * v12;   // adj00
        f2 adj1 = v02 * v12 - v01 * v22;   // adj01
        f2 adj2 = v01 * v12 - v02 * v11;   // adj02
        f2 adj3 = v00 * v22 - v02 * v02;   // adj11
        f2 adj4 = v01 * v02 - v00 * v12;   // adj12
        f2 adj5 = v00 * v11 - v01 * v01;   // adj22
        f2 det = v00 * adj0 + v01 * adj1 + v02 * adj2;
        f2 id;
        id.x = __builtin_amdgcn_rcpf(det.x);   // v_rcp_f32 (validated v3..v11)
        id.y = __builtin_amdgcn_rcpf(det.y);

        // --- X phase: channel at a time; next channel prefetched so its
        // latency hides under this channel's math (v2/v4 pattern). ---
        f2 termAcc = (f2){0.0f, 0.0f};
        #pragma unroll
        for (int c = 0; c < 3; ++c) {
            f2 Xnxt[3][2];
            if (c < 2) {
                #pragma unroll
                for (int r = 0; r < 3; ++r) {
                    const float* q = Xin + (c + 1) * HW + base + r * W;
                    Xnxt[r][0] = *(const f2*)q;
                    Xnxt[r][1] = *(const f2*)(q + 2);
                }
            }
            f2 S, SSw, W0, W1, W2;
            XSUM(Xcur, S) XXDOT(Xcur, SSw)
            XCDOT(Xcur, 0, W0) XCDOT(Xcur, 1, W1) XCDOT(Xcur, 2, W2)
            f2 u0 = W0 - S * mu0;
            f2 u1 = W1 - S * mu1;
            f2 u2 = W2 - S * mu2;
            f2 qa = u0 * (adj0 * u0 + adj1 * u1 + adj2 * u2)
                  + u1 * (adj1 * u0 + adj3 * u1 + adj4 * u2)
                  + u2 * (adj2 * u0 + adj4 * u1 + adj5 * u2);
            termAcc += SSw - (S * S + qa * id) * inv9;
            if (c < 2) {
                #pragma unroll
                for (int r = 0; r < 3; ++r) {
                    Xcur[r][0] = Xnxt[r][0];
                    Xcur[r][1] = Xnxt[r][1];
                }
            }
        }
        contrib = termAcc.x + termAcc.y;       // both windows valid
    }
#undef WSUM
#undef CSUM
#undef CDOT
#undef XSUM
#undef XXDOT
#undef XCDOT

    // Wave shuffle reduction -> cross-wave LDS -> ONE plain store per block.
    #pragma unroll
    for (int off = 32; off > 0; off >>= 1)
        contrib += __shfl_down(contrib, off, 64);

    __shared__ float wsum[4];
    const int tid = threadIdx.y * 32 + threadIdx.x;
    const int lane = tid & 63, wv = tid >> 6;
    if (lane == 0) wsum[wv] = contrib;
    __syncthreads();
    if (tid == 0)
        ws[swz] = wsum[0] + wsum[1] + wsum[2] + wsum[3];
}

// Tiny reducer: image b owns ws[b*512 .. b*512+511]. Writes loss[b] directly.
__global__ __launch_bounds__(256) void reduce_kernel(
    const float* __restrict__ ws, float* __restrict__ loss)
{
    const int b = blockIdx.x;
    const int t = threadIdx.x;
    float v = ws[b * 512 + t] + ws[b * 512 + 256 + t];
    #pragma unroll
    for (int off = 32; off > 0; off >>= 1)
        v += __shfl_down(v, off, 64);

    __shared__ float s[4];
    if ((t & 63) == 0) s[t >> 6] = v;
    __syncthreads();
    if (t == 0) loss[b] = s[0] + s[1] + s[2] + s[3];
}

extern "C" void kernel_launch(void* const* d_in, const int* in_sizes, int n_in,
                              void* d_out, int out_size, void* d_ws, size_t ws_size,
                              hipStream_t stream) {
    const float* outp = (const float*)d_in[0];   // output: (4,3,512,512) f32
    const float* cont = (const float*)d_in[1];   // content: (4,3,512,512) f32
    float* loss = (float*)d_out;                 // (4,1,1) f32
    float* ws   = (float*)d_ws;                  // 2048 floats of workspace

    dim3 block(32, 8, 1);
    dim3 grid(8, 64, 4);   // 256 thread-cols x 512 thread-rows x 4 images
    matting_loss_kernel<<<grid, block, 0, stream>>>(outp, cont, ws);
    reduce_kernel<<<dim3(4, 1, 1), dim3(256, 1, 1), 0, stream>>>(ws, loss);
}

// Round 11
// 13.768 us; speedup vs baseline: 1.0823x; 1.0465x over previous
//
#include <hip/hip_runtime.h>

#define EPSV 1e-7f

// v13: attack load DEMAND (the never-touched floor). v9-v12 plateau 14.4-14.9
// triangulates: marginal time==issue-cycles (slope 1), occupancy 2->4 waves
// neutral, regs neutral => residual is memory DELIVERY: 100 MB of L1/L2
// traffic (4x the 25MB unique: 3x vertical halo x ~1.3x horizontal) ~2.7us+
// at L2 agg BW. KY=2 vertical tiling: thread computes 2 vertically-adjacent
// window-pairs from 4 pixel rows: 24 f2 loads/pair (was 36, -33%); demand
// 67 MB. Per-window math BITWISE identical to v12 (same fma chains) --
// isolates the load-demand variable. Waves halve -> 4096 = one fully-resident
// round. Regs ~126 (Cb 48 + finals 40 + Xb 16 + temps) -- borderline 128,
// UNPINNED (v5 rule: no pin with <15-reg margin).
typedef float f2 __attribute__((ext_vector_type(2)));

__global__ __launch_bounds__(256) void matting_loss_kernel(
    const float* __restrict__ outp, const float* __restrict__ cont,
    float* __restrict__ ws)
{
    const int H = 512, W = 512, NW = 510;
    const int HW = H * W;

    // --- XCD swizzle (bijective: 1024 % 8 == 0); 2 XCDs per image,
    //     each owns a half-image row strip. ---
    const int lin = blockIdx.x + 8 * (blockIdx.y + 32 * blockIdx.z);
    const int swz = (lin & 7) * 128 + (lin >> 3);
    const int b   = swz >> 8;                       // image 0..3
    const int rem = swz & 255;
    const int gx  = (rem & 7) * 32 + threadIdx.x;   // 0..255 -> wx0 = 2*gx
    const int gg  = (rem >> 3) * 8 + threadIdx.y;   // 0..255 -> wy0 = 2*gg
    const int wx0 = gx * 2;
    const int wy0 = gg * 2;

    const float* Cin = cont + (size_t)b * 3 * HW;
    const float* Xin = outp + (size_t)b * 3 * HW;

    float contrib = 0.0f;
    const float inv9 = 1.0f / 9.0f;

#define WSUM(OUT, A0, A1) { f2 T_ = (A0) + (A1); (OUT).x = T_.x + (A0).y; (OUT).y = T_.y + (A1).x; }
#define CSUM(CH, R0, OUT) { \
    f2 A0_ = Cb[CH][R0][0] + Cb[CH][R0+1][0] + Cb[CH][R0+2][0]; \
    f2 A1_ = Cb[CH][R0][1] + Cb[CH][R0+1][1] + Cb[CH][R0+2][1]; \
    WSUM(OUT, A0_, A1_) }
#define CDOT(CA, CB_, R0, OUT) { \
    f2 A0_ = Cb[CA][R0][0]*Cb[CB_][R0][0] + Cb[CA][R0+1][0]*Cb[CB_][R0+1][0] + Cb[CA][R0+2][0]*Cb[CB_][R0+2][0]; \
    f2 A1_ = Cb[CA][R0][1]*Cb[CB_][R0][1] + Cb[CA][R0+1][1]*Cb[CB_][R0+1][1] + Cb[CA][R0+2][1]*Cb[CB_][R0+2][1]; \
    WSUM(OUT, A0_, A1_) }
#define XSUM(R0, OUT) { \
    f2 A0_ = Xb[R0][0] + Xb[R0+1][0] + Xb[R0+2][0]; \
    f2 A1_ = Xb[R0][1] + Xb[R0+1][1] + Xb[R0+2][1]; \
    WSUM(OUT, A0_, A1_) }
#define XXDOT(R0, OUT) { \
    f2 A0_ = Xb[R0][0]*Xb[R0][0] + Xb[R0+1][0]*Xb[R0+1][0] + Xb[R0+2][0]*Xb[R0+2][0]; \
    f2 A1_ = Xb[R0][1]*Xb[R0][1] + Xb[R0+1][1]*Xb[R0+1][1] + Xb[R0+2][1]*Xb[R0+2][1]; \
    WSUM(OUT, A0_, A1_) }
#define XCDOT(R0, K_, OUT) { \
    f2 A0_ = Xb[R0][0]*Cb[K_][R0][0] + Xb[R0+1][0]*Cb[K_][R0+1][0] + Xb[R0+2][0]*Cb[K_][R0+2][0]; \
    f2 A1_ = Xb[R0][1]*Cb[K_][R0][1] + Xb[R0+1][1]*Cb[K_][R0+1][1] + Xb[R0+2][1]*Cb[K_][R0+2][1]; \
    WSUM(OUT, A0_, A1_) }

    if (wy0 < NW && wx0 < NW) {   // gg<=254, gx<=254: windows wy0,wy0+1 x wx0,wx0+1 valid
        const int base = wy0 * W + wx0;

        // Load burst: 24 C f2 (3ch x 4 rows x 2 pairs); latency under moments.
        f2 Cb[3][4][2];
        #pragma unroll
        for (int ch = 0; ch < 3; ++ch)
            #pragma unroll
            for (int r = 0; r < 4; ++r) {
                const float* p = Cin + ch * HW + base + r * W;
                Cb[ch][r][0] = *(const f2*)p;
                Cb[ch][r][1] = *(const f2*)(p + 2);
            }

        // --- Moment phase, both window-rows (rows wr..wr+2) ---
        f2 mu0[2], mu1[2], mu2[2];
        f2 adj0[2], adj1[2], adj2[2], adj3[2], adj4[2], adj5[2], idet[2];
        #pragma unroll
        for (int wr = 0; wr < 2; ++wr) {
            f2 sI0, sI1, sI2, s00, s01, s02, s11, s12, s22;
            CSUM(0, wr, sI0) CSUM(1, wr, sI1) CSUM(2, wr, sI2)
            CDOT(0, 0, wr, s00) CDOT(0, 1, wr, s01) CDOT(0, 2, wr, s02)
            CDOT(1, 1, wr, s11) CDOT(1, 2, wr, s12) CDOT(2, 2, wr, s22)
            f2 m0 = sI0 * inv9, m1 = sI1 * inv9, m2 = sI2 * inv9;
            const float ed = EPSV * inv9;
            f2 v00 = s00 * inv9 - m0 * m0 + ed;
            f2 v01 = s01 * inv9 - m0 * m1;
            f2 v02 = s02 * inv9 - m0 * m2;
            f2 v11 = s11 * inv9 - m1 * m1 + ed;
            f2 v12 = s12 * inv9 - m1 * m2;
            f2 v22 = s22 * inv9 - m2 * m2 + ed;
            f2 a0 = v11 * v22 - v12 * v12;
            f2 a1 = v02 * v12 - v01 * v22;
            f2 a2 = v01 * v12 - v02 * v11;
            f2 det = v00 * a0 + v01 * a1 + v02 * a2;
            mu0[wr] = m0; mu1[wr] = m1; mu2[wr] = m2;
            adj0[wr] = a0; adj1[wr] = a1; adj2[wr] = a2;
            adj3[wr] = v00 * v22 - v02 * v02;
            adj4[wr] = v01 * v02 - v00 * v12;
            adj5[wr] = v00 * v11 - v01 * v01;
            f2 idv;
            idv.x = __builtin_amdgcn_rcpf(det.x);   // v_rcp_f32 (validated v3..v12)
            idv.y = __builtin_amdgcn_rcpf(det.y);
            idet[wr] = idv;
        }

        // --- X phase: per channel, 4 rows loaded once, both window-rows ---
        f2 termAcc = (f2){0.0f, 0.0f};
        #pragma unroll
        for (int c = 0; c < 3; ++c) {
            f2 Xb[4][2];
            #pragma unroll
            for (int r = 0; r < 4; ++r) {
                const float* q = Xin + c * HW + base + r * W;
                Xb[r][0] = *(const f2*)q;
                Xb[r][1] = *(const f2*)(q + 2);
            }
            #pragma unroll
            for (int wr = 0; wr < 2; ++wr) {
                f2 S, SSw, W0, W1, W2;
                XSUM(wr, S) XXDOT(wr, SSw)
                XCDOT(wr, 0, W0) XCDOT(wr, 1, W1) XCDOT(wr, 2, W2)
                f2 u0 = W0 - S * mu0[wr];
                f2 u1 = W1 - S * mu1[wr];
                f2 u2 = W2 - S * mu2[wr];
                f2 qa = u0 * (adj0[wr] * u0 + adj1[wr] * u1 + adj2[wr] * u2)
                      + u1 * (adj1[wr] * u0 + adj3[wr] * u1 + adj4[wr] * u2)
                      + u2 * (adj2[wr] * u0 + adj4[wr] * u1 + adj5[wr] * u2);
                termAcc += SSw - (S * S + qa * idet[wr]) * inv9;
            }
        }
        contrib = termAcc.x + termAcc.y;   // all 4 windows valid
    }
#undef WSUM
#undef CSUM
#undef CDOT
#undef XSUM
#undef XXDOT
#undef XCDOT

    // Wave shuffle reduction -> cross-wave LDS -> ONE plain store per block.
    #pragma unroll
    for (int off = 32; off > 0; off >>= 1)
        contrib += __shfl_down(contrib, off, 64);

    __shared__ float wsum[4];
    const int tid = threadIdx.y * 32 + threadIdx.x;
    const int lane = tid & 63, wv = tid >> 6;
    if (lane == 0) wsum[wv] = contrib;
    __syncthreads();
    if (tid == 0)
        ws[swz] = wsum[0] + wsum[1] + wsum[2] + wsum[3];
}

// Tiny reducer: image b owns ws[b*256 .. b*256+255]. Writes loss[b] directly.
__global__ __launch_bounds__(256) void reduce_kernel(
    const float* __restrict__ ws, float* __restrict__ loss)
{
    const int b = blockIdx.x;
    const int t = threadIdx.x;
    float v = ws[b * 256 + t];
    #pragma unroll
    for (int off = 32; off > 0; off >>= 1)
        v += __shfl_down(v, off, 64);

    __shared__ float s[4];
    if ((t & 63) == 0) s[t >> 6] = v;
    __syncthreads();
    if (t == 0) loss[b] = s[0] + s[1] + s[2] + s[3];
}

extern "C" void kernel_launch(void* const* d_in, const int* in_sizes, int n_in,
                              void* d_out, int out_size, void* d_ws, size_t ws_size,
                              hipStream_t stream) {
    const float* outp = (const float*)d_in[0];   // output: (4,3,512,512) f32
    const float* cont = (const float*)d_in[1];   // content: (4,3,512,512) f32
    float* loss = (float*)d_out;                 // (4,1,1) f32
    float* ws   = (float*)d_ws;                  // 1024 floats of workspace

    dim3 block(32, 8, 1);
    dim3 grid(8, 32, 4);   // 256 x-threads x 256 row-groups x 4 images
    matting_loss_kernel<<<grid, block, 0, stream>>>(outp, cont, ws);
    reduce_kernel<<<dim3(4, 1, 1), dim3(256, 1, 1), 0, stream>>>(ws, loss);
}